// Round 4
// baseline (86.710 us; speedup 1.0000x reference)
//
#include <hip/hip_runtime.h>

// CompiledLogicNet fully fused, ZERO-WORKSPACE version, v4.
// One block per u32 batch-column (32 samples). State [16384] u32 in LDS,
// double-buffered; gathers = LDS reads. Raw idx/neg descriptors are read
// directly from global (uint4), with CROSS-BARRIER prefetch: each layer's
// stage-0/1 descriptor loads are issued during the PREVIOUS layer (register
// destinations only -> no LDS hazard across __syncthreads), so their L2
// latency hides under a full layer of DS work instead of stalling the layer
// entry. Stage 3 is predicated (t<928): gates 16000..16383 are pad, never
// computed, never written, never read downstream.
// GroupSum: one wave per class, b128 reads + CSA planes + shfl_xor butterfly.

#define NIN   784
#define WIDTH 16000
#define SW    16384    // padded width (16 * TPB)
#define NH    4
#define NC    10
#define GPC   1600     // gates per class
#define NBLK  128      // u32 columns: 4096 batch / 32
#define TPB   1024

typedef unsigned int u32;

__launch_bounds__(TPB, 4)
__global__ void net_kernel(const int* __restrict__ x,
                           const int* __restrict__ ia0, const int* __restrict__ ib0,
                           const int* __restrict__ n0,
                           const int* __restrict__ iah, const int* __restrict__ ibh,
                           const int* __restrict__ nh,
                           int* __restrict__ out) {
    __shared__ __align__(16) u32 xw[NIN];
    __shared__ __align__(16) u32 bufA[SW];
    __shared__ __align__(16) u32 bufB[SW];

    int w = blockIdx.x;
    int t = threadIdx.x;
    const bool p3 = (t < 928);          // stage-3 real gates: 4*(t+3072) < 16000

    // register pipeline state (lives across layers; all indices fold after unroll)
    uint4 ta[2], tb[2];                 // raw ia/ib quads, double-buffered
    uint4 rn0[3], rn1[3];               // raw neg quads, 3-slot rotation
    u32 av[12], bv[12];                 // gathered operands, 3 slots x 4 gates

#define LOADRAW(PA, PB, PN, II, B, SLOT) { \
        int ii = (II); \
        ta[B]     = *(const uint4*)((PA) + 4 * ii); \
        tb[B]     = *(const uint4*)((PB) + 4 * ii); \
        rn0[SLOT] = *(const uint4*)((PN) + 8 * ii); \
        rn1[SLOT] = *(const uint4*)((PN) + 8 * ii + 4); }

#define ISSUE(B, SLOT) { \
        av[4*(SLOT)+0] = cur[(u32)ta[B].x]; bv[4*(SLOT)+0] = cur[(u32)tb[B].x]; \
        av[4*(SLOT)+1] = cur[(u32)ta[B].y]; bv[4*(SLOT)+1] = cur[(u32)tb[B].y]; \
        av[4*(SLOT)+2] = cur[(u32)ta[B].z]; bv[4*(SLOT)+2] = cur[(u32)tb[B].z]; \
        av[4*(SLOT)+3] = cur[(u32)ta[B].w]; bv[4*(SLOT)+3] = cur[(u32)tb[B].w]; }

#define CONSUME(S, SLOT) { \
        uint4 r; \
        r.x = (av[4*(SLOT)+0] ^ (0u - (u32)(rn0[SLOT].x != 0))) & (bv[4*(SLOT)+0] ^ (0u - (u32)(rn0[SLOT].y != 0))); \
        r.y = (av[4*(SLOT)+1] ^ (0u - (u32)(rn0[SLOT].z != 0))) & (bv[4*(SLOT)+1] ^ (0u - (u32)(rn0[SLOT].w != 0))); \
        r.z = (av[4*(SLOT)+2] ^ (0u - (u32)(rn1[SLOT].x != 0))) & (bv[4*(SLOT)+2] ^ (0u - (u32)(rn1[SLOT].y != 0))); \
        r.w = (av[4*(SLOT)+3] ^ (0u - (u32)(rn1[SLOT].z != 0))) & (bv[4*(SLOT)+3] ^ (0u - (u32)(rn1[SLOT].w != 0))); \
        *(uint4*)(dst + 4 * (t + (S) * TPB)) = r; }

    // ---- prefetch layer-0 stages 0,1 FIRST (slots 0,1), then pack ----
    LOADRAW(ia0, ib0, n0, t,       0, 0);
    LOADRAW(ia0, ib0, n0, t + TPB, 1, 1);

    // pack: xw[i] bit r = x[w*32+r][i] (coalesced along i)
    if (t < NIN) {
        const int* base = x + (size_t)(w * 32) * NIN + t;
        u32 acc = 0;
#pragma unroll
        for (int r = 0; r < 32; ++r)
            acc |= (base[(size_t)r * NIN] != 0 ? 1u : 0u) << r;
        xw[t] = acc;
    }
    __syncthreads();

    // ---- 5 layers, ping-pong LDS, pipelined gathers + cross-barrier prefetch ----
    u32* cur = xw;
#pragma unroll
    for (int l = 0; l <= NH; ++l) {
        u32* dst = (l & 1) ? bufB : bufA;     // A,B,A,B,A -> result in bufA
        const int sp = l % 3, sq = (l + 1) % 3, sr = (l + 2) % 3;
        const int* pa = l ? iah + (size_t)(l - 1) * WIDTH     : ia0;
        const int* pb = l ? ibh + (size_t)(l - 1) * WIDTH     : ib0;
        const int* pn = l ? nh  + (size_t)(l - 1) * 2 * WIDTH : n0;

        ISSUE(0, sp);                                    // stage0 gathers (ta[0] prefetched)
        LOADRAW(pa, pb, pn, t + 2 * TPB, 0, sr);         // stage2 raw
        ISSUE(1, sq);                                    // stage1 gathers
        CONSUME(0, sp);                                  // -> slot sp free
        if (p3) LOADRAW(pa, pb, pn, t + 3 * TPB, 1, sp); // stage3 raw (real gates only)
        ISSUE(0, sr);                                    // stage2 gathers
        CONSUME(1, sq);                                  // -> slot sq free
        if (p3) ISSUE(1, sp);                            // stage3 gathers
        CONSUME(2, sr);                                  // -> slot sr free
        if (l < NH) {                                    // prefetch NEXT layer stages 0,1
            const int* qa = iah + (size_t)l * WIDTH;
            const int* qb = ibh + (size_t)l * WIDTH;
            const int* qn = nh  + (size_t)l * 2 * WIDTH;
            LOADRAW(qa, qb, qn, t,       0, sq);         // next stage0 -> slot (l+1)%3
            LOADRAW(qa, qb, qn, t + TPB, 1, sr);         // next stage1 -> slot (l+2)%3
        }
        if (p3) CONSUME(3, sp);
        __syncthreads();
        cur = dst;
    }
#undef LOADRAW
#undef ISSUE
#undef CONSUME
    u32* res = bufA;

    // ---- GroupSum: one wave per class, CSA planes + shfl_xor butterfly ----
    int wave = t >> 6, lane = t & 63;
    if (wave < NC) {
        int c = wave;
        const u32* base = res + c * GPC;
        u32 p0 = 0, p1 = 0, p2 = 0, p3v = 0, p4 = 0;
#define CSA5(VAL) { u32 cy = (VAL); u32 s; \
        s = p0;  p0  = s ^ cy; cy = s & cy; \
        s = p1;  p1  = s ^ cy; cy = s & cy; \
        s = p2;  p2  = s ^ cy; cy = s & cy; \
        s = p3v; p3v = s ^ cy; cy = s & cy; \
        s = p4;  p4  = s ^ cy; }
#pragma unroll
        for (int k = 0; k < 6; ++k) {
            uint4 v = *(const uint4*)(base + 4 * lane + 256 * k);  // b128, conflict-free
            CSA5(v.x); CSA5(v.y); CSA5(v.z); CSA5(v.w);
        }
        CSA5(base[1536 + lane]);   // 25 values per lane, fits 5 planes
#undef CSA5

        // butterfly: merge 64 lanes' plane sets; planes grow 5 -> 11
        u32 pl[11];
        pl[0] = p0; pl[1] = p1; pl[2] = p2; pl[3] = p3v; pl[4] = p4;
#pragma unroll
        for (int s = 0; s < 6; ++s) {
            int np = 5 + s;
            u32 q[11];
#pragma unroll
            for (int i = 0; i < 11; ++i) if (i < np) q[i] = __shfl_xor(pl[i], 1 << s, 64);
            u32 carry = 0;
#pragma unroll
            for (int i = 0; i < 11; ++i) if (i < np) {
                u32 a = pl[i], b = q[i];
                u32 xr = a ^ b;
                pl[i] = xr ^ carry;
                carry = (a & b) | (carry & xr);
            }
            pl[np] = carry;
        }

        // every lane now holds the 11-plane vertical count over 1600 gates
        if (lane < 32) {
            int cntv = 0;
#pragma unroll
            for (int i = 0; i < 11; ++i) cntv += (int)((pl[i] >> lane) & 1u) << i;
            out[((size_t)w * 32 + lane) * NC + c] = cntv;
        }
    }
}

// ---------------------------------------------------------------------------
extern "C" void kernel_launch(void* const* d_in, const int* in_sizes, int n_in,
                              void* d_out, int out_size, void* d_ws, size_t ws_size,
                              hipStream_t stream) {
    const int* x      = (const int*)d_in[0];  // [4096,784] 0/1
    const int* idx_a0 = (const int*)d_in[1];  // [16000]
    const int* idx_b0 = (const int*)d_in[2];  // [16000]
    const int* neg0   = (const int*)d_in[3];  // [16000,2]
    const int* idx_a  = (const int*)d_in[4];  // [4,16000]
    const int* idx_b  = (const int*)d_in[5];  // [4,16000]
    const int* neg    = (const int*)d_in[6];  // [4,16000,2]
    int* out = (int*)d_out;                   // [4096,10]

    (void)d_ws; (void)ws_size;                // workspace intentionally UNUSED

    net_kernel<<<NBLK, TPB, 0, stream>>>(
        x, idx_a0, idx_b0, neg0, idx_a, idx_b, neg, out);
}